// Round 3
// baseline (361.894 us; speedup 1.0000x reference)
//
#include <hip/hip_runtime.h>

typedef unsigned short u16;
typedef unsigned int u32;
typedef __attribute__((ext_vector_type(8))) short bf16x8;
typedef __attribute__((ext_vector_type(4))) float f32x4;
typedef __attribute__((ext_vector_type(4))) u16 u16x4;
typedef __attribute__((ext_vector_type(8))) u16 u16x8;

#define B_ 64
#define R_ 2
#define T_ 32
#define N_ 128
#define C_ 64

__device__ __forceinline__ u16 f2bf(float f) {
  u32 u = __builtin_bit_cast(u32, f);
  u = (u + 0x7FFFu + ((u >> 16) & 1u)) >> 16;
  return (u16)u;
}
__device__ __forceinline__ float bf2f(u16 h) {
  u32 u = ((u32)h) << 16;
  return __builtin_bit_cast(float, u);
}

#define MFMA __builtin_amdgcn_mfma_f32_16x16x32_bf16

// ---- A-chunk loads, R1 mapping (thread owns 32 floats of one row): feeds
// conflict-free AT transpose-write + 2-shuffle rowsum.
__device__ __forceinline__ void a_load(float4* av, const float* Aslice, int ch, int tid) {
  const int arow = tid >> 2, aseg = tid & 3;
  const float* ap = Aslice + (size_t)(ch * 64 + arow) * N_ + aseg * 32;
#pragma unroll
  for (int j = 0; j < 8; ++j) av[j] = *(const float4*)(ap + 4 * j);
}

// ---- flat-coalesced copy loads/stores (4KB contiguous per wave-instr)
__device__ __forceinline__ void c_load(float4* cv, const float* Aslice, int ch, int tid) {
  const float* p = Aslice + ch * 8192 + tid * 4;
#pragma unroll
  for (int j = 0; j < 8; ++j) cv[j] = *(const float4*)(p + j * 1024);
}
__device__ __forceinline__ void c_store(const float4* cv, float* Oslice, int ch, int tid) {
  float* p = Oslice + ch * 8192 + tid * 4;
#pragma unroll
  for (int j = 0; j < 8; ++j) *(float4*)(p + j * 1024) = cv[j];
}

// ---- rowsum -> dinv, AT transpose-write with dinv[n] + I folded (2-way banks)
__device__ __forceinline__ void at_write(const float4* av, int ch, int tid,
                                         u16 (*AT)[72], float* dinv) {
  const int arow = tid >> 2, aseg = tid & 3;
  const int n = ch * 64 + arow;
  float part = 0.f;
#pragma unroll
  for (int j = 0; j < 8; ++j) part += (av[j].x + av[j].y) + (av[j].z + av[j].w);
  part += __shfl_xor(part, 1);
  part += __shfl_xor(part, 2);
  const float d = rsqrtf(part + 1.0f);
  if (aseg == 0) dinv[n] = d;
  const int col = arow ^ (aseg << 4);
#pragma unroll
  for (int j = 0; j < 8; ++j) {
#pragma unroll
    for (int k = 0; k < 4; ++k) {
      const int m = aseg * 32 + 4 * j + k;
      float v = ((const float*)&av[j])[k];
      if (m == n) v += 1.0f;
      AT[m][col] = f2bf(v * d);
    }
  }
}

__device__ __forceinline__ void load_wg(bf16x8 wf[2][2], const float* wg, int r,
                                        int wr, int lr, int lg) {
#pragma unroll
  for (int kk = 0; kk < 2; ++kk)
#pragma unroll
    for (int mr = 0; mr < 2; ++mr) {
      const float* p = wg + ((size_t)(r * C_ + 32 * wr + 16 * mr + lr)) * C_ + 32 * kk + 8 * lg;
      float4 a = *(const float4*)p, b = *(const float4*)(p + 4);
      bf16x8 f;
      f[0] = (short)f2bf(a.x); f[1] = (short)f2bf(a.y);
      f[2] = (short)f2bf(a.z); f[3] = (short)f2bf(a.w);
      f[4] = (short)f2bf(b.x); f[5] = (short)f2bf(b.y);
      f[6] = (short)f2bf(b.z); f[7] = (short)f2bf(b.w);
      wf[kk][mr] = f;
    }
}

// mm1: TMP[o][n^( (o&3)<<4 )] = sum_c W[o][c]*X[c][n] + bias
__device__ __forceinline__ void mm1(u16 (*TMP)[128], const bf16x8 wf[2][2],
                                    const bf16x8 bfr[2][4], const float* bgr,
                                    int wr, int wc, int lr, int lg) {
  f32x4 acc1[2][4] = {};
#pragma unroll
  for (int kk = 0; kk < 2; ++kk)
#pragma unroll
    for (int mr = 0; mr < 2; ++mr)
#pragma unroll
      for (int nc = 0; nc < 4; ++nc)
        acc1[mr][nc] = MFMA(wf[kk][mr], bfr[kk][nc], acc1[mr][nc], 0, 0, 0);
#pragma unroll
  for (int mr = 0; mr < 2; ++mr) {
    const int o0 = 32 * wr + 16 * mr + 4 * lg;
#pragma unroll
    for (int nc = 0; nc < 4; ++nc) {
      const int n = 64 * wc + 16 * nc + lr;
#pragma unroll
      for (int i = 0; i < 4; ++i)
        TMP[o0 + i][n ^ (i << 4)] = f2bf(acc1[mr][nc][i] + bgr[o0 + i]);
    }
  }
}

// mm2 full-K (both chunks resident, no mid-barriers), then dinv[m]-fold
__device__ __forceinline__ void mm2_fold(f32x4 acc2[2][4], const u16 (*TMP)[128],
                                         const u16 (*ATa)[72], const u16 (*ATb)[72],
                                         const float* dinv, int wr, int wc, int lr, int lg) {
  f32x4 accr[2][4] = {};
#pragma unroll
  for (int kk = 0; kk < 4; ++kk) {
    const u16 (*ATc)[72] = (kk < 2) ? ATa : ATb;
    const int kkin = kk & 1;
    bf16x8 af[2], bfr[4];
#pragma unroll
    for (int mr = 0; mr < 2; ++mr) {
      const int c = 32 * wr + 16 * mr + lr;
      const int colT = (32 * kk + 8 * lg) ^ ((lr & 3) << 4);
      af[mr] = *(const bf16x8*)&TMP[c][colT];
    }
#pragma unroll
    for (int nc = 0; nc < 4; ++nc) {
      const int m = 64 * wc + 16 * nc + lr;
      const int colA = (32 * kkin + 8 * lg) ^ (((m >> 5) & 3) << 4);
      bfr[nc] = *(const bf16x8*)&ATc[m][colA];
    }
#pragma unroll
    for (int mr = 0; mr < 2; ++mr)
#pragma unroll
      for (int nc = 0; nc < 4; ++nc)
        accr[mr][nc] = MFMA(af[mr], bfr[nc], accr[mr][nc], 0, 0, 0);
  }
#pragma unroll
  for (int nc = 0; nc < 4; ++nc) {
    const float dm = dinv[64 * wc + 16 * nc + lr];
#pragma unroll
    for (int mr = 0; mr < 2; ++mr)
#pragma unroll
      for (int i = 0; i < 4; ++i)
        acc2[mr][nc][i] += dm * accr[mr][nc][i];
  }
}

// ---------------------------------------------------------------------------
// K1: per (b,t): A copy (coalesced), normalized laplacian, gcn MFMA, bmm MFMA.
// LDS = 18432*2 + 16384 + 512 + 512 = 54272 B -> 3 blocks/CU.
// ---------------------------------------------------------------------------
__global__ __launch_bounds__(256, 3) void k_gcn(
    const float* __restrict__ x, const float* __restrict__ A,
    const float* __restrict__ wg, const float* __restrict__ bg,
    float* __restrict__ outA, u16* __restrict__ wsX) {
  __shared__ __align__(16) u16 ATa[N_][72];
  __shared__ __align__(16) u16 ATb[N_][72];   // also transient X^T stage
  __shared__ __align__(16) u16 TMP[C_][128];  // also epilogue stage
  __shared__ float dinv[N_];
  __shared__ float bgc[R_][C_];

  const int tid = threadIdx.x, bi = blockIdx.x;
  const int b = bi >> 5, t = bi & 31;
  const int lane = tid & 63, wv = tid >> 6;
  const int wr = wv >> 1, wc = wv & 1;
  const int lr = lane & 15, lg = lane >> 4;

  const size_t Asl0 = ((size_t)((b * R_ + 0) * T_ + t)) * (N_ * N_);
  const size_t Asl1 = ((size_t)((b * R_ + 1) * T_ + t)) * (N_ * N_);

  // ---- t0: issue x slice, r0-ch0 (both mappings), W0, bias
  float4 xv[8];
  {
    const int c = tid & 63, ub = tid >> 6;
    const float* xp = x + ((size_t)(b * C_ + c) * T_ + t) * N_ + 32 * ub;
#pragma unroll
    for (int j = 0; j < 8; ++j) xv[j] = *(const float4*)(xp + 4 * j);
  }
  float4 av[8], cv[8];
  a_load(av, A + Asl0, 0, tid);
  c_load(cv, A + Asl0, 0, tid);
  bf16x8 wf0[2][2];
  load_wg(wf0, wg, 0, wr, lr, lg);
  if (tid < R_ * C_) ((float*)bgc)[tid] = bg[tid];

  // ---- P0: X^T into ATb space (transient)
  u16 (*XTv)[64] = (u16(*)[64])ATb;
  {
    const int c = tid & 63, ub = tid >> 6;
#pragma unroll
    for (int j = 0; j < 8; ++j) {
      const int n0 = 32 * ub + 4 * j;
      XTv[n0 + 0][c] = f2bf(xv[j].x);
      XTv[n0 + 1][c ^ 16] = f2bf(xv[j].y);
      XTv[n0 + 2][c ^ 32] = f2bf(xv[j].z);
      XTv[n0 + 3][c ^ 48] = f2bf(xv[j].w);
    }
  }
  __syncthreads();

  // ---- P1: extract mm1 B-frags (r-independent); consume r0-ch0; issue r0-ch1
  bf16x8 bfr[2][4];
#pragma unroll
  for (int kk = 0; kk < 2; ++kk)
#pragma unroll
    for (int nc = 0; nc < 4; ++nc) {
      const int n = 64 * wc + 16 * nc + lr;
      const int col = (32 * kk + 8 * lg) ^ ((lr & 3) << 4);
      bfr[kk][nc] = *(const bf16x8*)&XTv[n][col];
    }
  at_write(av, 0, tid, ATa, dinv);
  c_store(cv, outA + Asl0, 0, tid);
  float4 av1[8], cv1[8];
  a_load(av1, A + Asl0, 1, tid);
  c_load(cv1, A + Asl0, 1, tid);
  __syncthreads();

  // ---- P2: mm1 r0 -> TMP; consume r0-ch1; issue r1-ch0
  mm1(TMP, wf0, bfr, bgc[0], wr, wc, lr, lg);
  at_write(av1, 1, tid, ATb, dinv);
  c_store(cv1, outA + Asl0, 1, tid);
  a_load(av, A + Asl1, 0, tid);
  c_load(cv, A + Asl1, 0, tid);
  __syncthreads();

  // ---- P3: mm2 r0 (full K) + fold; load W1; issue r1-ch1
  f32x4 acc2[2][4] = {};
  bf16x8 wf1[2][2];
  load_wg(wf1, wg, 1, wr, lr, lg);
  a_load(av1, A + Asl1, 1, tid);
  c_load(cv1, A + Asl1, 1, tid);
  mm2_fold(acc2, TMP, ATa, ATb, dinv, wr, wc, lr, lg);
  __syncthreads();

  // ---- P4: consume r1-ch0, mm1 r1 (covers ch1 latency), consume r1-ch1
  at_write(av, 0, tid, ATa, dinv);
  c_store(cv, outA + Asl1, 0, tid);
  mm1(TMP, wf1, bfr, bgc[1], wr, wc, lr, lg);
  at_write(av1, 1, tid, ATb, dinv);
  c_store(cv1, outA + Asl1, 1, tid);
  __syncthreads();

  // ---- P5: mm2 r1 + fold
  mm2_fold(acc2, TMP, ATa, ATb, dinv, wr, wc, lr, lg);
  __syncthreads();

  // ---- P6: epilogue via LDS round-trip -> coalesced u16x8 stores
  u16* stage = &TMP[0][0];
#pragma unroll
  for (int mr = 0; mr < 2; ++mr)
#pragma unroll
    for (int nc = 0; nc < 4; ++nc) {
      const int m = 64 * wc + 16 * nc + lr;
      const int c0 = 32 * wr + 16 * mr + 4 * lg;
#pragma unroll
      for (int i = 0; i < 4; ++i)
        stage[m * 64 + ((c0 + i) ^ ((m & 7) << 3))] = f2bf(acc2[mr][nc][i]);
    }
  __syncthreads();
  {
    u16* wp = wsX + ((size_t)(b * T_ + t) * N_) * C_;
#pragma unroll
    for (int it = 0; it < 4; ++it) {
      const int idx = it * 2048 + tid * 8;
      const int m = idx >> 6, a = idx & 63;
      u16x8 v = *(const u16x8*)&stage[m * 64 + a];
      *(u16x8*)(wp + m * 64 + (a ^ ((m & 7) << 3))) = v;
    }
  }
}

// ---------------------------------------------------------------------------
// K2: per (b,t): h = prelu(x_comb); out = prelu(conv3_T(h) + b_tcn + x)
// ---------------------------------------------------------------------------
__global__ __launch_bounds__(256, 3) void k_tcn(
    const u16* __restrict__ wsX, const float* __restrict__ x,
    const float* __restrict__ wt, const float* __restrict__ bt,
    const float* __restrict__ a_tcn, const float* __restrict__ a_out,
    float* __restrict__ out) {
  __shared__ __align__(16) u16 HT[N_][200];
  const int tid = threadIdx.x, bi = blockIdx.x;
  const int b = bi >> 5, t = bi & 31;
  const int lane = tid & 63, wv = tid >> 6;
  const int wr = wv >> 1, wc = wv & 1;
  const int lr = lane & 15, lg = lane >> 4;
  const float at = a_tcn[0], ao = a_out[0];

  bf16x8 wfr[6][2];
#pragma unroll
  for (int kk = 0; kk < 6; ++kk) {
    const int dt = kk >> 1;
    const int ci0 = (32 * kk + 8 * lg) & 63;
#pragma unroll
    for (int mr = 0; mr < 2; ++mr) {
      const int co = 32 * wr + 16 * mr + lr;
      const float* p = wt + ((size_t)co * C_ + ci0) * 3 + dt;
      float e[8];
#pragma unroll
      for (int j = 0; j < 8; ++j) e[j] = p[3 * j];
      bf16x8 f;
#pragma unroll
      for (int j = 0; j < 8; ++j) f[j] = (short)f2bf(e[j]);
      wfr[kk][mr] = f;
    }
  }

#pragma unroll
  for (int dt = 0; dt < 3; ++dt) {
    const int t2 = t + dt - 1;
    const bool ok = (t2 >= 0) && (t2 < T_);
    const u16* p = wsX + ((size_t)(b * T_ + (ok ? t2 : 0)) * N_) * C_;
    u16x4 hv[8];
#pragma unroll
    for (int it = 0; it < 8; ++it) {
      const int idx = it * 256 + tid;
      const int n = idx >> 4, c4 = (idx & 15) * 4;
      u16x4 z = {0, 0, 0, 0};
      hv[it] = ok ? *(const u16x4*)(p + n * C_ + c4) : z;
    }
#pragma unroll
    for (int it = 0; it < 8; ++it) {
      const int idx = it * 256 + tid;
      const int n = idx >> 4, c4 = (idx & 15) * 4;
      u16x4 o;
#pragma unroll
      for (int j = 0; j < 4; ++j) {
        float f = bf2f(hv[it][j]);
        o[j] = f2bf(f < 0.f ? at * f : f);
      }
      *(u16x4*)&HT[n][dt * 64 + c4] = o;
    }
  }
  __syncthreads();

  f32x4 acc[2][4] = {};
#pragma unroll
  for (int kk = 0; kk < 6; ++kk) {
    bf16x8 bfr[4];
#pragma unroll
    for (int nc = 0; nc < 4; ++nc)
      bfr[nc] = *(const bf16x8*)&HT[64 * wc + 16 * nc + lr][32 * kk + 8 * lg];
#pragma unroll
    for (int mr = 0; mr < 2; ++mr)
#pragma unroll
      for (int nc = 0; nc < 4; ++nc)
        acc[mr][nc] = MFMA(wfr[kk][mr], bfr[nc], acc[mr][nc], 0, 0, 0);
  }

#pragma unroll
  for (int mr = 0; mr < 2; ++mr) {
    const int co0 = 32 * wr + 16 * mr + 4 * lg;
    float bts[4];
#pragma unroll
    for (int i = 0; i < 4; ++i) bts[i] = bt[co0 + i];
#pragma unroll
    for (int nc = 0; nc < 4; ++nc) {
      const int n = 64 * wc + 16 * nc + lr;
#pragma unroll
      for (int i = 0; i < 4; ++i) {
        const size_t gi = ((size_t)(b * C_ + co0 + i) * T_ + t) * N_ + n;
        float v = acc[mr][nc][i] + bts[i] + x[gi];
        out[gi] = (v < 0.f) ? ao * v : v;
      }
    }
  }
}

extern "C" void kernel_launch(void* const* d_in, const int* in_sizes, int n_in,
                              void* d_out, int out_size, void* d_ws, size_t ws_size,
                              hipStream_t stream) {
  const float* x = (const float*)d_in[0];
  const float* A = (const float*)d_in[1];
  const float* wg = (const float*)d_in[2];
  const float* bg = (const float*)d_in[3];
  const float* wt = (const float*)d_in[4];
  const float* bt = (const float*)d_in[5];
  const float* atc = (const float*)d_in[6];
  const float* aoc = (const float*)d_in[7];
  float* out = (float*)d_out;
  float* outA = out + (size_t)B_ * C_ * T_ * N_;  // second tuple element: A copy
  u16* wsX = (u16*)d_ws;                          // bf16 x_comb, (B,T,N,C)

  k_gcn<<<B_ * T_, 256, 0, stream>>>(x, A, wg, bg, outA, wsX);
  k_tcn<<<B_ * T_, 256, 0, stream>>>(wsX, x, wt, bt, atc, aoc, out);
}

// Round 4
// 209.087 us; speedup vs baseline: 1.7308x; 1.7308x over previous
//
#include <hip/hip_runtime.h>

typedef unsigned short u16;
typedef unsigned int u32;
typedef __attribute__((ext_vector_type(8))) short bf16x8;
typedef __attribute__((ext_vector_type(4))) float f32x4;
typedef __attribute__((ext_vector_type(4))) u16 u16x4;
typedef __attribute__((ext_vector_type(8))) u16 u16x8;

#define B_ 64
#define R_ 2
#define T_ 32
#define N_ 128
#define C_ 64

__device__ __forceinline__ u16 f2bf(float f) {
  u32 u = __builtin_bit_cast(u32, f);
  u = (u + 0x7FFFu + ((u >> 16) & 1u)) >> 16;
  return (u16)u;
}
__device__ __forceinline__ float bf2f(u16 h) {
  u32 u = ((u32)h) << 16;
  return __builtin_bit_cast(float, u);
}

#define MFMA __builtin_amdgcn_mfma_f32_16x16x32_bf16

// async global->LDS, 16B per lane, LDS dest = wave-uniform base + lane*16
#define STG16(gsrc, ldst)                                                   \
  __builtin_amdgcn_global_load_lds(                                         \
      (const __attribute__((address_space(1))) u32*)(gsrc),                 \
      (__attribute__((address_space(3))) u32*)(ldst), 16, 0, 0)

#define ASM_WAIT_LGKM asm volatile("s_waitcnt lgkmcnt(0)" ::: "memory")
#define ASM_WAIT_VM(N) asm volatile("s_waitcnt vmcnt(" #N ") lgkmcnt(0)" ::: "memory")
#define ASM_FENCE asm volatile("" ::: "memory")
#define BARRIER __builtin_amdgcn_s_barrier()

// stage one 16KB A-chunk (32 rows x 128 f32): 4 calls/wave, 1KB each
__device__ __forceinline__ void stage_chunk(const float* Abase, float* AFb,
                                            int w, int lane) {
#pragma unroll
  for (int j = 0; j < 4; ++j) {
    const int off = (w * 4 + j) * 256;  // floats
    STG16(Abase + off + lane * 4, AFb + off);
  }
}

__device__ __forceinline__ void load_wg(bf16x8 wf[2][2], const float* wg, int r,
                                        int wr, int lr, int lg) {
#pragma unroll
  for (int kk = 0; kk < 2; ++kk)
#pragma unroll
    for (int mr = 0; mr < 2; ++mr) {
      const float* p = wg + ((size_t)(r * C_ + 32 * wr + 16 * mr + lr)) * C_ + 32 * kk + 8 * lg;
      float4 a = *(const float4*)p, b = *(const float4*)(p + 4);
      bf16x8 f;
      f[0] = (short)f2bf(a.x); f[1] = (short)f2bf(a.y);
      f[2] = (short)f2bf(a.z); f[3] = (short)f2bf(a.w);
      f[4] = (short)f2bf(b.x); f[5] = (short)f2bf(b.y);
      f[6] = (short)f2bf(b.z); f[7] = (short)f2bf(b.w);
      wf[kk][mr] = f;
    }
}

// mm1: TMP[o][n ^ ((o&3)<<4)] = sum_c W[o][c]*X[c][n] + bias[o]
__device__ __forceinline__ void mm1f(u16 (*TMP)[128], const bf16x8 wf[2][2],
                                     const bf16x8 bfr[2][4], const float4 bias[2],
                                     int wr, int wc, int lr, int lg) {
  f32x4 acc1[2][4] = {};
#pragma unroll
  for (int kk = 0; kk < 2; ++kk)
#pragma unroll
    for (int mr = 0; mr < 2; ++mr)
#pragma unroll
      for (int nc = 0; nc < 4; ++nc)
        acc1[mr][nc] = MFMA(wf[kk][mr], bfr[kk][nc], acc1[mr][nc], 0, 0, 0);
#pragma unroll
  for (int mr = 0; mr < 2; ++mr) {
    const int o0 = 32 * wr + 16 * mr + 4 * lg;
    const float bb[4] = {bias[mr].x, bias[mr].y, bias[mr].z, bias[mr].w};
#pragma unroll
    for (int nc = 0; nc < 4; ++nc) {
      const int n = 64 * wc + 16 * nc + lr;
#pragma unroll
      for (int i = 0; i < 4; ++i)
        TMP[o0 + i][n ^ (i << 4)] = f2bf(acc1[mr][nc][i] + bb[i]);
    }
  }
}

// ---------------------------------------------------------------------------
// K1: per (b,t). A streamed via global_load_lds (3-buffer ring, counted vmcnt).
// Per chunk: CP1 = coalesced copy + rowsum->dinv; CP2 = in-register bf16
// conversion of A_norm^T fragments + MFMA. LDS = 49152+16384+512 = 66048 B.
// ---------------------------------------------------------------------------
__global__ __launch_bounds__(256, 2) void k_gcn(
    const float* __restrict__ x, const float* __restrict__ A,
    const float* __restrict__ wg, const float* __restrict__ bg,
    float* __restrict__ outA, u16* __restrict__ wsX) {
  __shared__ __align__(16) float AF[3][32 * 128];
  __shared__ __align__(16) u16 TMP[C_][128];
  __shared__ float dinv[N_];

  const int tid = threadIdx.x, bi = blockIdx.x;
  const int b = bi >> 5, t = bi & 31;
  const int lane = tid & 63, w = tid >> 6;
  const int wr = w >> 1, wc = w & 1;
  const int lr = lane & 15, lg = lane >> 4;

  // ---- prologue: x slice, weights, bias (register loads, consumed here)
  float4 xv[8];
  {
    const int c = tid & 63, ub = tid >> 6;
    const float* xp = x + ((size_t)(b * C_ + c) * T_ + t) * N_ + 32 * ub;
#pragma unroll
    for (int j = 0; j < 8; ++j) xv[j] = *(const float4*)(xp + 4 * j);
  }
  bf16x8 wf0[2][2], wf1[2][2];
  load_wg(wf0, wg, 0, wr, lr, lg);
  load_wg(wf1, wg, 1, wr, lr, lg);
  float4 bias[R_][2];
#pragma unroll
  for (int r = 0; r < R_; ++r)
#pragma unroll
    for (int mr = 0; mr < 2; ++mr)
      bias[r][mr] = *(const float4*)(bg + r * C_ + 32 * wr + 16 * mr + 4 * lg);

  // ---- X^T (bf16, swizzled) into TMP region
  u16 (*XT)[64] = (u16(*)[64])TMP;
  {
    const int c = tid & 63, ub = tid >> 6;
#pragma unroll
    for (int j = 0; j < 8; ++j) {
      const int n0 = 32 * ub + 4 * j;
      XT[n0 + 0][c] = f2bf(xv[j].x);
      XT[n0 + 1][c ^ 16] = f2bf(xv[j].y);
      XT[n0 + 2][c ^ 32] = f2bf(xv[j].z);
      XT[n0 + 3][c ^ 48] = f2bf(xv[j].w);
    }
  }
  // issue chunks 0,1 (r0 ch0/ch1)
  {
    const size_t Asl0 = ((size_t)(b * R_) * T_ + t) * (size_t)(N_ * N_);
    stage_chunk(A + Asl0, AF[0], w, lane);
    stage_chunk(A + Asl0 + 4096, AF[1], w, lane);
  }
  ASM_WAIT_LGKM;
  BARRIER;

  // ---- extract mm1 B-fragments (r-independent)
  bf16x8 bfrx[2][4];
#pragma unroll
  for (int kk = 0; kk < 2; ++kk)
#pragma unroll
    for (int nc = 0; nc < 4; ++nc) {
      const int n = 64 * wc + 16 * nc + lr;
      const int col = (32 * kk + 8 * lg) ^ ((lr & 3) << 4);
      bfrx[kk][nc] = *(const bf16x8*)&XT[n][col];
    }
  ASM_WAIT_LGKM;
  BARRIER;

  // ---- mm1 r0 -> TMP (covers chunk0 flight time)
  mm1f(TMP, wf0, bfrx, bias[0], wr, wc, lr, lg);
  ASM_WAIT_VM(4);  // chunk0 landed (chunk1 still in flight)
  BARRIER;

  f32x4 acc2[2][4] = {};
  f32x4 accr[2][4];

#pragma unroll 1
  for (int q = 0; q < 8; ++q) {
    const int r = q >> 2, ch = q & 3;
    const size_t Asl = ((size_t)((b * R_ + r) * T_ + t)) * (size_t)(N_ * N_);
    float* AFb = AF[q % 3];

    // ---- CP1: coalesced copy + rowsum -> dinv ; (mm1 r1 at q==4)
    {
      float* dst = outA + Asl + ch * 4096;
#pragma unroll
      for (int i = 0; i < 4; ++i) {
        const int off = i * 1024 + tid * 4;
        float4 v = *(const float4*)(AFb + off);
        *(float4*)(dst + off) = v;
        float s = (v.x + v.y) + (v.z + v.w);
        s += __shfl_xor(s, 1); s += __shfl_xor(s, 2); s += __shfl_xor(s, 4);
        s += __shfl_xor(s, 8); s += __shfl_xor(s, 16);
        if ((lane & 31) == 0) dinv[32 * ch + 8 * i + (tid >> 5)] = rsqrtf(s + 1.0f);
      }
      if (q == 4) mm1f(TMP, wf1, bfrx, bias[1], wr, wc, lr, lg);
      ASM_WAIT_LGKM;
      BARRIER;
    }

    // ---- CP2: issue chunk q+2; build A_norm^T frags in-register; MFMA
    {
      if (q < 6) {
        const int q2 = q + 2;
        const size_t Asl2 = ((size_t)((b * R_ + (q2 >> 2)) * T_ + t)) * (size_t)(N_ * N_);
        stage_chunk(A + Asl2 + (q2 & 3) * 4096, AF[q2 % 3], w, lane);
      }
      if ((q & 3) == 0) {
#pragma unroll
        for (int mr = 0; mr < 2; ++mr)
#pragma unroll
          for (int nc = 0; nc < 4; ++nc) accr[mr][nc] = (f32x4){0.f, 0.f, 0.f, 0.f};
      }
      float dv[8];
#pragma unroll
      for (int i = 0; i < 8; ++i) dv[i] = dinv[32 * ch + 8 * lg + i];
      bf16x8 bfrv[4];
#pragma unroll
      for (int nc = 0; nc < 4; ++nc) {
        const int m = 64 * wc + 16 * nc + lr;
        bf16x8 f;
#pragma unroll
        for (int i = 0; i < 8; ++i) {
          const int nl = 8 * lg + i;
          float v = AFb[nl * 128 + m];
          v = (m == 32 * ch + nl) ? (v + 1.0f) : v;
          f[i] = (short)f2bf(v * dv[i]);
        }
        bfrv[nc] = f;
      }
#pragma unroll
      for (int mr = 0; mr < 2; ++mr) {
        const int c = 32 * wr + 16 * mr + lr;
        const int colT = (32 * ch + 8 * lg) ^ ((lr & 3) << 4);
        bf16x8 af = *(const bf16x8*)&TMP[c][colT];
#pragma unroll
        for (int nc = 0; nc < 4; ++nc)
          accr[mr][nc] = MFMA(af, bfrv[nc], accr[mr][nc], 0, 0, 0);
      }
      if ((q & 3) == 3) {  // fold dinv[m], accumulate into acc2
#pragma unroll
        for (int nc = 0; nc < 4; ++nc) {
          const float dm = dinv[64 * wc + 16 * nc + lr];
#pragma unroll
          for (int mr = 0; mr < 2; ++mr)
#pragma unroll
            for (int i = 0; i < 4; ++i) acc2[mr][nc][i] += dm * accr[mr][nc][i];
        }
      }
      if (q < 6) {
        ASM_WAIT_VM(8);   // chunk q+1 landed; stores(q)+loads(q+2) may fly
      } else if (q == 6) {
        ASM_WAIT_VM(4);   // chunk 7 landed
      } else {
        ASM_FENCE;
      }
      BARRIER;
    }
  }

  // ---- epilogue: stage in TMP (swizzled) -> coalesced u16x8 wsX stores
  u16* stage = &TMP[0][0];
#pragma unroll
  for (int mr = 0; mr < 2; ++mr)
#pragma unroll
    for (int nc = 0; nc < 4; ++nc) {
      const int m = 64 * wc + 16 * nc + lr;
      const int c0 = 32 * wr + 16 * mr + 4 * lg;
#pragma unroll
      for (int i = 0; i < 4; ++i)
        stage[m * 64 + ((c0 + i) ^ ((m & 7) << 3))] = f2bf(acc2[mr][nc][i]);
    }
  ASM_WAIT_LGKM;
  BARRIER;
  {
    u16* wp = wsX + ((size_t)(b * T_ + t) * N_) * C_;
#pragma unroll
    for (int it = 0; it < 4; ++it) {
      const int idx = it * 2048 + tid * 8;
      const int m = idx >> 6, a = idx & 63;
      u16x8 v = *(const u16x8*)&stage[m * 64 + a];
      *(u16x8*)(wp + m * 64 + (a ^ ((m & 7) << 3))) = v;
    }
  }
}

// ---------------------------------------------------------------------------
// K2: per (b,t): h = prelu(x_comb); out = prelu(conv3_T(h) + b_tcn + x)
// ---------------------------------------------------------------------------
__global__ __launch_bounds__(256, 3) void k_tcn(
    const u16* __restrict__ wsX, const float* __restrict__ x,
    const float* __restrict__ wt, const float* __restrict__ bt,
    const float* __restrict__ a_tcn, const float* __restrict__ a_out,
    float* __restrict__ out) {
  __shared__ __align__(16) u16 HT[N_][200];
  const int tid = threadIdx.x, bi = blockIdx.x;
  const int b = bi >> 5, t = bi & 31;
  const int lane = tid & 63, wv = tid >> 6;
  const int wr = wv >> 1, wc = wv & 1;
  const int lr = lane & 15, lg = lane >> 4;
  const float at = a_tcn[0], ao = a_out[0];

  bf16x8 wfr[6][2];
#pragma unroll
  for (int kk = 0; kk < 6; ++kk) {
    const int dt = kk >> 1;
    const int ci0 = (32 * kk + 8 * lg) & 63;
#pragma unroll
    for (int mr = 0; mr < 2; ++mr) {
      const int co = 32 * wr + 16 * mr + lr;
      const float* p = wt + ((size_t)co * C_ + ci0) * 3 + dt;
      float e[8];
#pragma unroll
      for (int j = 0; j < 8; ++j) e[j] = p[3 * j];
      bf16x8 f;
#pragma unroll
      for (int j = 0; j < 8; ++j) f[j] = (short)f2bf(e[j]);
      wfr[kk][mr] = f;
    }
  }

#pragma unroll
  for (int dt = 0; dt < 3; ++dt) {
    const int t2 = t + dt - 1;
    const bool ok = (t2 >= 0) && (t2 < T_);
    const u16* p = wsX + ((size_t)(b * T_ + (ok ? t2 : 0)) * N_) * C_;
    u16x4 hv[8];
#pragma unroll
    for (int it = 0; it < 8; ++it) {
      const int idx = it * 256 + tid;
      const int n = idx >> 4, c4 = (idx & 15) * 4;
      u16x4 z = {0, 0, 0, 0};
      hv[it] = ok ? *(const u16x4*)(p + n * C_ + c4) : z;
    }
#pragma unroll
    for (int it = 0; it < 8; ++it) {
      const int idx = it * 256 + tid;
      const int n = idx >> 4, c4 = (idx & 15) * 4;
      u16x4 o;
#pragma unroll
      for (int j = 0; j < 4; ++j) {
        float f = bf2f(hv[it][j]);
        o[j] = f2bf(f < 0.f ? at * f : f);
      }
      *(u16x4*)&HT[n][dt * 64 + c4] = o;
    }
  }
  __syncthreads();

  f32x4 acc[2][4] = {};
#pragma unroll
  for (int kk = 0; kk < 6; ++kk) {
    bf16x8 bfr[4];
#pragma unroll
    for (int nc = 0; nc < 4; ++nc)
      bfr[nc] = *(const bf16x8*)&HT[64 * wc + 16 * nc + lr][32 * kk + 8 * lg];
#pragma unroll
    for (int mr = 0; mr < 2; ++mr)
#pragma unroll
      for (int nc = 0; nc < 4; ++nc)
        acc[mr][nc] = MFMA(wfr[kk][mr], bfr[nc], acc[mr][nc], 0, 0, 0);
  }

#pragma unroll
  for (int mr = 0; mr < 2; ++mr) {
    const int co0 = 32 * wr + 16 * mr + 4 * lg;
    float bts[4];
#pragma unroll
    for (int i = 0; i < 4; ++i) bts[i] = bt[co0 + i];
#pragma unroll
    for (int nc = 0; nc < 4; ++nc) {
      const int n = 64 * wc + 16 * nc + lr;
#pragma unroll
      for (int i = 0; i < 4; ++i) {
        const size_t gi = ((size_t)(b * C_ + co0 + i) * T_ + t) * N_ + n;
        float v = acc[mr][nc][i] + bts[i] + x[gi];
        out[gi] = (v < 0.f) ? ao * v : v;
      }
    }
  }
}

extern "C" void kernel_launch(void* const* d_in, const int* in_sizes, int n_in,
                              void* d_out, int out_size, void* d_ws, size_t ws_size,
                              hipStream_t stream) {
  const float* x = (const float*)d_in[0];
  const float* A = (const float*)d_in[1];
  const float* wg = (const float*)d_in[2];
  const float* bg = (const float*)d_in[3];
  const float* wt = (const float*)d_in[4];
  const float* bt = (const float*)d_in[5];
  const float* atc = (const float*)d_in[6];
  const float* aoc = (const float*)d_in[7];
  float* out = (float*)d_out;
  float* outA = out + (size_t)B_ * C_ * T_ * N_;  // second tuple element: A copy
  u16* wsX = (u16*)d_ws;                          // bf16 x_comb, (B,T,N,C)

  k_gcn<<<B_ * T_, 256, 0, stream>>>(x, A, wg, bg, outA, wsX);
  k_tcn<<<B_ * T_, 256, 0, stream>>>(wsX, x, wt, bt, atc, aoc, out);
}